// Round 4
// baseline (280.530 us; speedup 1.0000x reference)
//
#include <hip/hip_runtime.h>
#include <hip/hip_bf16.h>

// ---------------------------------------------------------------------------
// DimNet via bf16 MFMA implicit GEMM, halo-stationary A + pipelined B weights.
//   Pn  = padded input, NHWC bf16  [2][104][104][32]
//   Bn  = relu(conv2a), NHWC bf16  [2][100][100][192]  (g' = uv*20+mc)
//   Wa  = w2b transposed [tap25][oc448][c192] bf16
//   Wb1 = w1  transposed [tap81][oc448][c32]  bf16
// conv_mfma: 128-thread blocks (2 waves), each wave 128px x 64oc (acc[8][4]).
// A-halo staged once per channel-chunk in slot-major LDS [4][pix]; taps read
// shifted views (uniform offset). Weights: 4-buffer distance-2 counted vmcnt.
// ---------------------------------------------------------------------------

typedef __attribute__((ext_vector_type(8))) unsigned short ushort8;
typedef __attribute__((ext_vector_type(8))) __bf16 bf16x8;
typedef __attribute__((ext_vector_type(4))) float f32x4;

#define NB 2
#define HPAD_A 448   // cells/slot phase A (12*36=432 used)
#define HPAD_B 576   // cells/slot phase B (16*36 exact)

static __device__ __forceinline__ unsigned short f2bf(float f) {
    __hip_bfloat16 h = __float2bfloat16(f);
    return *reinterpret_cast<unsigned short*>(&h);
}
static __device__ __forceinline__ float bf2f(unsigned short u) {
    unsigned int v = ((unsigned int)u) << 16;
    return __uint_as_float(v);
}
static __device__ __forceinline__ void gload16(const unsigned short* g, unsigned short* l) {
    __builtin_amdgcn_global_load_lds(
        (const __attribute__((address_space(1))) unsigned int*)(const void*)g,
        (__attribute__((address_space(3))) unsigned int*)(void*)l, 16, 0, 0);
}

// ---------------- pad: NHWC bf16 + planar bf16 ----------------
__global__ __launch_bounds__(256) void pad_kernel(const float* __restrict__ pic,
                                                  unsigned short* __restrict__ Pn,
                                                  unsigned short* __restrict__ Pp) {
    int idx = blockIdx.x * 256 + threadIdx.x;
    if (idx >= NB * 104 * 104) return;
    int x = idx % 104;
    int y = (idx / 104) % 104;
    int b = idx / (104 * 104);
    unsigned short vals[32];
    bool inter = (y >= 4 && y < 100 && x >= 4 && x < 100);
#pragma unroll
    for (int c = 0; c < 25; ++c) {
        float v = inter ? pic[((b * 25 + c) * 96 + (y - 4)) * 96 + (x - 4)] : 0.5f;
        vals[c] = f2bf(v);
        Pp[((b * 25 + c) * 104 + y) * 104 + x] = vals[c];
    }
#pragma unroll
    for (int c = 25; c < 32; ++c) vals[c] = 0;
    ushort8* dst = (ushort8*)(Pn + idx * 32);
#pragma unroll
    for (int j = 0; j < 4; ++j) dst[j] = *(ushort8*)&vals[j * 8];
}

// ---------------- weight prep ----------------
#define NWA (25 * 448 * 192)
#define NWB (81 * 448 * 32)
__global__ __launch_bounds__(256) void prep_w_kernel(const float* __restrict__ w2b,
                                                     const float* __restrict__ w1,
                                                     unsigned short* __restrict__ Wa,
                                                     unsigned short* __restrict__ Wb1) {
    int idx = blockIdx.x * 256 + threadIdx.x;
    if (idx < NWA) {
        int c   = idx % 192;
        int oc  = (idx / 192) % 448;
        int tap = idx / (192 * 448);
        float v = 0.f;
        if (oc < 400 && c < 180) {
            int mc = c % 20, uv = c / 20;              // g' = uv*20 + mc
            v = w2b[oc * 4500 + (mc * 9 + uv) * 25 + tap];
        }
        Wa[idx] = f2bf(v);
    } else {
        int k = idx - NWA;
        if (k >= NWB) return;
        int c   = k % 32;
        int oc  = (k / 32) % 448;
        int tap = k / (32 * 448);
        float v = (oc < 400 && c < 25) ? w1[oc * 2025 + c * 81 + tap] : 0.f;
        Wb1[k] = f2bf(v);
    }
}

// ---------------- conv2a (fp32 VALU, 1.6 GFLOP) ----------------
__global__ __launch_bounds__(256) void conv2a_kernel(const unsigned short* __restrict__ Pp,
                                                     const float* __restrict__ w2a,
                                                     const float* __restrict__ b2a,
                                                     unsigned short* __restrict__ Bn) {
    __shared__ float sIn[9 * 20 * 21];
    __shared__ float sW[20 * 225];
    const int b   = blockIdx.z;
    const int uv  = blockIdx.y;
    const int u   = uv / 3, v = uv % 3;
    const int tx0 = (blockIdx.x % 7) * 16;
    const int ty0 = (blockIdx.x / 7) * 16;
    const int tid = threadIdx.x;

    for (int i = tid; i < 20 * 225; i += 256) sW[i] = w2a[i];
    for (int i = tid; i < 9 * 20 * 20; i += 256) {
        int ch9 = i / 400;
        int r   = (i / 20) % 20;
        int cl  = i % 20;
        int c   = (u + ch9 / 3) * 5 + (v + ch9 % 3);
        int gy  = min(ty0 + r, 103);
        int gx  = min(tx0 + cl, 103);
        sIn[ch9 * 420 + r * 21 + cl] = bf2f(Pp[((b * 25 + c) * 104 + gy) * 104 + gx]);
    }
    __syncthreads();

    const int mcg = tid >> 6;
    const int pid = tid & 63;
    const int px  = (pid & 7) * 2;
    const int py  = (pid >> 3) * 2;

    float acc[5][2][2];
#pragma unroll
    for (int m = 0; m < 5; m++)
#pragma unroll
        for (int r = 0; r < 2; r++)
#pragma unroll
            for (int c = 0; c < 2; c++) acc[m][r][c] = 0.f;

    for (int ch9 = 0; ch9 < 9; ++ch9) {
        const float* in = &sIn[ch9 * 420];
#pragma unroll
        for (int dy = 0; dy < 5; ++dy) {
            float ra[6], rb[6];
#pragma unroll
            for (int k = 0; k < 6; k++) {
                ra[k] = in[(py + dy) * 21 + px + k];
                rb[k] = in[(py + 1 + dy) * 21 + px + k];
            }
#pragma unroll
            for (int dx = 0; dx < 5; ++dx) {
#pragma unroll
                for (int m = 0; m < 5; m++) {
                    float w = sW[(mcg * 5 + m) * 225 + ch9 * 25 + dy * 5 + dx];
                    acc[m][0][0] += ra[dx] * w;
                    acc[m][0][1] += ra[dx + 1] * w;
                    acc[m][1][0] += rb[dx] * w;
                    acc[m][1][1] += rb[dx + 1] * w;
                }
            }
        }
    }

#pragma unroll
    for (int m = 0; m < 5; m++) {
        int mc = mcg * 5 + m;
        float bias = b2a[mc];
        int gp = uv * 20 + mc;
#pragma unroll
        for (int r = 0; r < 2; r++) {
            int y = ty0 + py + r;
            if (y >= 100) continue;
#pragma unroll
            for (int c = 0; c < 2; c++) {
                int x = tx0 + px + c;
                if (x >= 100) continue;
                Bn[((b * 100 + y) * 100 + x) * 192 + gp] = f2bf(fmaxf(acc[m][r][c] + bias, 0.f));
                if (uv == 0 && mcg == 3) {
#pragma unroll
                    for (int z = 0; z < 12; ++z)
                        Bn[((b * 100 + y) * 100 + x) * 192 + 180 + z] = 0;
                }
            }
        }
    }
}

// ---------------- halo-stationary MFMA conv ----------------
__global__ __launch_bounds__(128, 2) void conv_mfma_kernel(
    const unsigned short* __restrict__ Pn, const unsigned short* __restrict__ Bn,
    const unsigned short* __restrict__ Wa, const unsigned short* __restrict__ Wb1,
    const float* __restrict__ b1, const float* __restrict__ b2b,
    float* __restrict__ out) {
    __shared__ __align__(16) unsigned short sHalo[4 * HPAD_B * 8];  // 36,864 B
    __shared__ __align__(16) unsigned short sB[4][2048];            // 4 x 4,096 B

    const int tid = threadIdx.x;
    const int lane = tid & 63, w = tid >> 6;
    const int l15 = lane & 15, lhi = lane >> 4;
    const int ocB = blockIdx.y;
    const int pb  = blockIdx.x;
    const int b   = pb / 36;
    const int t36 = pb % 36;
    const int ty0 = (t36 / 3) * 8;
    const int tx0 = (t36 % 3) * 32;

    // A-frag base (ushort units), slot-major [kslot][row*36+col], phase-A stride
    int vA = (lhi * HPAD_A + w * 144 + l15) * 8;
    // B-frag base within one weight buffer (ushort units)
    const int vB = (lhi * 64 + l15) * 8;
    // staging per-lane weight offsets
    const int vWoffA = (ocB * 64 + lane) * 192;
    const int vWoffB = (ocB * 64 + lane) * 32;

    // bias preload (oldest vmem ops; drained by first vmcnt)
    float bb2[4], bb1[4];
#pragma unroll
    for (int n = 0; n < 4; ++n) {
        int oc  = ocB * 64 + n * 16 + l15;
        int occ = oc < 400 ? oc : 399;
        bb2[n] = b2b[occ];
        bb1[n] = b1[occ];
    }

    f32x4 acc[8][4] = {};

    auto stage_B = [&](int t) {
        int buf = t & 3;
#pragma unroll
        for (int s2 = 0; s2 < 2; ++s2) {
            int slot = w * 2 + s2;
            const unsigned short* src;
            if (t < 150) {
                int cc = t / 25, tap = t % 25;
                src = Wa + (size_t)tap * (448 * 192) + vWoffA + cc * 32 + slot * 8;
            } else {
                int u = t - 150, dy, dx;
                if (u < 45) { dy = u / 5; dx = u % 5; }
                else { int u2 = u - 45; dy = u2 >> 2; dx = 5 + (u2 & 3); }
                src = Wb1 + (size_t)(dy * 9 + dx) * (448 * 32) + vWoffB + slot * 8;
            }
            gload16(src, &sB[buf][slot * 512]);
        }
    };

    auto stage_halo = [&](int seg) {
        if (seg < 6) {  // phase A: Bn, 12 rows x 36 cols, pad to 448 cells/slot
#pragma unroll
            for (int s2 = 0; s2 < 2; ++s2) {
                int slot = w * 2 + s2;
                for (int L2 = 0; L2 < 7; ++L2) {
                    int p = L2 * 64 + lane;
                    if (p >= 432) p = 0;
                    int hy = (p * 58255) >> 21;       // p/36
                    int hx = p - hy * 36;
                    const unsigned short* src =
                        Bn + ((size_t)((b * 100 + ty0 + hy) * 100 + tx0 + hx)) * 192 +
                        seg * 32 + slot * 8;
                    gload16(src, &sHalo[(slot * HPAD_A + L2 * 64) * 8]);
                }
            }
        } else {        // phase B: Pn, 16 rows x 36 cols (seg7 origin +5), 576 exact
            int cx = tx0 + (seg == 7 ? 5 : 0);
#pragma unroll
            for (int s2 = 0; s2 < 2; ++s2) {
                int slot = w * 2 + s2;
                for (int L2 = 0; L2 < 9; ++L2) {
                    int p = L2 * 64 + lane;
                    int hy = (p * 58255) >> 21;       // p/36
                    int hx = p - hy * 36;
                    int gx = cx + hx;
                    gx = gx > 103 ? 103 : gx;         // seg7 last col never read
                    const unsigned short* src =
                        Pn + ((size_t)((b * 104 + ty0 + hy) * 104 + gx)) * 32 + slot * 8;
                    gload16(src, &sHalo[(slot * HPAD_B + L2 * 64) * 8]);
                }
            }
        }
    };

    auto compute = [&](int bufIdx, int tapU) {
        bf16x8 af[8], bv[4];
        const unsigned short* ha = &sHalo[vA + tapU];
#pragma unroll
        for (int m = 0; m < 8; ++m)
            af[m] = *(const bf16x8*)&ha[(m >> 1) * 288 + (m & 1) * 128];
        const unsigned short* hb = &sB[bufIdx][vB];
#pragma unroll
        for (int n = 0; n < 4; ++n) bv[n] = *(const bf16x8*)&hb[n * 128];
        __builtin_amdgcn_s_setprio(1);
#pragma unroll
        for (int m = 0; m < 8; ++m)
#pragma unroll
            for (int n = 0; n < 4; ++n)
                acc[m][n] = __builtin_amdgcn_mfma_f32_16x16x32_bf16(af[m], bv[n],
                                                                    acc[m][n], 0, 0, 0);
        __builtin_amdgcn_s_setprio(0);
    };

#define STEPM(S, TAPU, VN)                                       \
    {                                                            \
        if ((S) + 2 < 231) stage_B((S) + 2);                     \
        asm volatile("s_waitcnt vmcnt(" #VN ")" ::: "memory");   \
        asm volatile("s_barrier" ::: "memory");                  \
        compute((S) & 3, TAPU);                                  \
    }

    stage_halo(0);
    stage_B(0);
    stage_B(1);

    // -------- phase A: 6 channel-chunks x 25 taps --------
    for (int cc = 0; cc < 6; ++cc) {
        int s0 = cc * 25;
        if (cc) {
            asm volatile("s_barrier" ::: "memory");  // all reads of old halo done
            stage_halo(cc);
            STEPM(s0, 0, 2);
        } else {
            STEPM(0, 0, 4);
        }
        for (int k = 1; k < 25; ++k) {
            int dy = k / 5, dx = k - dy * 5;
            STEPM(s0 + k, (dy * 36 + dx) * 8, 4);
        }
    }

    // -------- p2 = relu(p2 + b2b) --------
#pragma unroll
    for (int m = 0; m < 8; ++m)
#pragma unroll
        for (int n = 0; n < 4; ++n)
#pragma unroll
            for (int i = 0; i < 4; ++i)
                acc[m][n][i] = fmaxf(acc[m][n][i] + bb2[n], 0.f);

    vA += lhi * ((HPAD_B - HPAD_A) * 8);  // switch to phase-B slot stride

    // -------- phase B1: taps dy 0..8, dx 0..4 (45 steps) --------
    asm volatile("s_barrier" ::: "memory");
    stage_halo(6);
    STEPM(150, 0, 2);
    for (int k = 1; k < 45; ++k) {
        int dy = k / 5, dx = k - dy * 5;
        STEPM(150 + k, (dy * 36 + dx) * 8, 4);
    }

    // -------- phase B2: taps dy 0..8, dx 5..8 (36 steps) --------
    asm volatile("s_barrier" ::: "memory");
    stage_halo(7);
    STEPM(195, 0, 2);
    for (int k = 1; k < 34; ++k) {
        int dy = k >> 2, dx = k & 3;
        STEPM(195 + k, (dy * 36 + dx) * 8, 4);
    }
    STEPM(229, (8 * 36 + 2) * 8, 2);
    STEPM(230, (8 * 36 + 3) * 8, 0);
#undef STEPM

    // -------- epilogue: (p1+p2+b1)/2, pixel-shuffled --------
#pragma unroll
    for (int n = 0; n < 4; ++n) {
        int oc = ocB * 64 + n * 16 + l15;
        if (oc >= 400) continue;
        float bv = bb1[n];
        int c25 = oc >> 4, r1 = (oc >> 2) & 3, r2 = oc & 3;
#pragma unroll
        for (int m = 0; m < 8; ++m) {
#pragma unroll
            for (int i = 0; i < 4; ++i) {
                int p  = w * 128 + m * 16 + lhi * 4 + i;
                int py = ty0 + (p >> 5), px = tx0 + (p & 31);
                out[((b * 25 + c25) * 384 + py * 4 + r1) * 384 + px * 4 + r2] =
                    (acc[m][n][i] + bv) * 0.5f;
            }
        }
    }
}

extern "C" void kernel_launch(void* const* d_in, const int* in_sizes, int n_in,
                              void* d_out, int out_size, void* d_ws, size_t ws_size,
                              hipStream_t stream) {
    const float* pic = (const float*)d_in[0];
    const float* w1  = (const float*)d_in[1];
    const float* b1  = (const float*)d_in[2];
    const float* w2a = (const float*)d_in[3];
    const float* b2a = (const float*)d_in[4];
    const float* w2b = (const float*)d_in[5];
    const float* b2b = (const float*)d_in[6];
    float* out = (float*)d_out;

    char* ws = (char*)d_ws;
    unsigned short* Pn  = (unsigned short*)(ws);             // 1,384,448 B
    unsigned short* Bn  = (unsigned short*)(ws + 1384448);   // 7,680,000 B
    unsigned short* Wa  = (unsigned short*)(ws + 9064448);   // 4,300,800 B
    unsigned short* Wb1 = (unsigned short*)(ws + 13365248);  // 2,322,432 B
    unsigned short* Pp  = Wa;  // planar bf16 P aliases Wa (dead before prep_w)

    pad_kernel<<<(NB * 104 * 104 + 255) / 256, 256, 0, stream>>>(pic, Pn, Pp);
    conv2a_kernel<<<dim3(49, 9, NB), 256, 0, stream>>>(Pp, w2a, b2a, Bn);
    prep_w_kernel<<<(NWA + NWB + 255) / 256, 256, 0, stream>>>(w2b, w1, Wa, Wb1);
    conv_mfma_kernel<<<dim3(72, 7), 128, 0, stream>>>(Pn, Bn, Wa, Wb1, b1, b2b, out);
}

// Round 5
// 171.666 us; speedup vs baseline: 1.6342x; 1.6342x over previous
//
#include <hip/hip_runtime.h>
#include <hip/hip_bf16.h>

// ---------------------------------------------------------------------------
// DimNet via bf16 MFMA implicit GEMM.
//   Halo-stationary A in LDS (one buffer, 8 segments, barriers only at swaps).
//   Weights pre-packed in MFMA-fragment order -> direct coalesced global loads
//   (L1-resident, depth-1 register prefetch). No weight LDS, no vmcnt games.
//   Pn  = padded input  NHWC bf16 [2][104][104][32]
//   Bn  = relu(conv2a)  NHWC bf16 [2][100][100][192] (g' = uv*20+mc)
//   WpA = w2b packed [cc6][tap25][ocb7][frag4][lane64][8]
//   WpB = w1  packed [tap81 visit-order][ocb7][frag4][lane64][8]
// conv_mfma: 256 threads (4 waves), block = 256px(8x32) x 64oc,
//   wave w owns rows 2w..2w+1; acc[4][4] per thread.
// ---------------------------------------------------------------------------

typedef __attribute__((ext_vector_type(8))) unsigned short ushort8;
typedef __attribute__((ext_vector_type(8))) __bf16 bf16x8;
typedef __attribute__((ext_vector_type(4))) float f32x4;

#define NB 2
#define HSLOT 576          // cells per k-slot (16 rows x 36 cols)
#define WST 14336          // ushorts per tap in packed weights (7*4*64*8)

static __device__ __forceinline__ unsigned short f2bf(float f) {
    __hip_bfloat16 h = __float2bfloat16(f);
    return *reinterpret_cast<unsigned short*>(&h);
}
static __device__ __forceinline__ float bf2f(unsigned short u) {
    unsigned int v = ((unsigned int)u) << 16;
    return __uint_as_float(v);
}
static __device__ __forceinline__ void gload16(const unsigned short* g, unsigned short* l) {
    __builtin_amdgcn_global_load_lds(
        (const __attribute__((address_space(1))) unsigned int*)(const void*)g,
        (__attribute__((address_space(3))) unsigned int*)(void*)l, 16, 0, 0);
}

// ---------------- pad: NHWC bf16 + planar bf16 ----------------
__global__ __launch_bounds__(256) void pad_kernel(const float* __restrict__ pic,
                                                  unsigned short* __restrict__ Pn,
                                                  unsigned short* __restrict__ Pp) {
    int idx = blockIdx.x * 256 + threadIdx.x;
    if (idx >= NB * 104 * 104) return;
    int x = idx % 104;
    int y = (idx / 104) % 104;
    int b = idx / (104 * 104);
    unsigned short vals[32];
    bool inter = (y >= 4 && y < 100 && x >= 4 && x < 100);
#pragma unroll
    for (int c = 0; c < 25; ++c) {
        float v = inter ? pic[((b * 25 + c) * 96 + (y - 4)) * 96 + (x - 4)] : 0.5f;
        vals[c] = f2bf(v);
        Pp[((b * 25 + c) * 104 + y) * 104 + x] = vals[c];
    }
#pragma unroll
    for (int c = 25; c < 32; ++c) vals[c] = 0;
    ushort8* dst = (ushort8*)(Pn + idx * 32);
#pragma unroll
    for (int j = 0; j < 4; ++j) dst[j] = *(ushort8*)&vals[j * 8];
}

// ---------------- weight prep: pack in MFMA-fragment order ----------------
#define NWA (6 * 25 * 7 * 4 * 64 * 8)   // 2,150,400
#define NWB (81 * 7 * 4 * 64 * 8)       // 1,161,216
__global__ __launch_bounds__(256) void prep_w_kernel(const float* __restrict__ w2b,
                                                     const float* __restrict__ w1,
                                                     unsigned short* __restrict__ WpA,
                                                     unsigned short* __restrict__ WpB) {
    int idx = blockIdx.x * 256 + threadIdx.x;
    if (idx < NWA) {
        int e = idx & 7, lane = (idx >> 3) & 63, n = (idx >> 9) & 3;
        int r = idx >> 11;
        int ocb = r % 7; r /= 7;
        int tap = r % 25; int cc = r / 25;
        int oc = ocb * 64 + n * 16 + (lane & 15);
        int k  = cc * 32 + (lane >> 4) * 8 + e;      // g' channel
        float v = 0.f;
        if (oc < 400 && k < 180) {
            int mc = k % 20, uv = k / 20;            // g' = uv*20 + mc
            v = w2b[oc * 4500 + (mc * 9 + uv) * 25 + tap];
        }
        WpA[idx] = f2bf(v);
    } else {
        int kx = idx - NWA;
        if (kx >= NWB) return;
        int e = kx & 7, lane = (kx >> 3) & 63, n = (kx >> 9) & 3;
        int r = kx >> 11;
        int ocb = r % 7; int tp = r / 7;             // visit order 0..80
        int dy, dx;
        if (tp < 45) { dy = tp / 5; dx = tp % 5; }
        else { int u = tp - 45; dy = u >> 2; dx = 5 + (u & 3); }
        int oc = ocb * 64 + n * 16 + (lane & 15);
        int c  = (lane >> 4) * 8 + e;
        float v = (oc < 400 && c < 25) ? w1[oc * 2025 + c * 81 + (dy * 9 + dx)] : 0.f;
        WpB[kx] = f2bf(v);
    }
}

// ---------------- conv2a (fp32 VALU, 1.6 GFLOP) ----------------
__global__ __launch_bounds__(256) void conv2a_kernel(const unsigned short* __restrict__ Pp,
                                                     const float* __restrict__ w2a,
                                                     const float* __restrict__ b2a,
                                                     unsigned short* __restrict__ Bn) {
    __shared__ float sIn[9 * 20 * 21];
    __shared__ float sW[20 * 225];
    const int b   = blockIdx.z;
    const int uv  = blockIdx.y;
    const int u   = uv / 3, v = uv % 3;
    const int tx0 = (blockIdx.x % 7) * 16;
    const int ty0 = (blockIdx.x / 7) * 16;
    const int tid = threadIdx.x;

    for (int i = tid; i < 20 * 225; i += 256) sW[i] = w2a[i];
    for (int i = tid; i < 9 * 20 * 20; i += 256) {
        int ch9 = i / 400;
        int r   = (i / 20) % 20;
        int cl  = i % 20;
        int c   = (u + ch9 / 3) * 5 + (v + ch9 % 3);
        int gy  = min(ty0 + r, 103);
        int gx  = min(tx0 + cl, 103);
        sIn[ch9 * 420 + r * 21 + cl] = bf2f(Pp[((b * 25 + c) * 104 + gy) * 104 + gx]);
    }
    __syncthreads();

    const int mcg = tid >> 6;
    const int pid = tid & 63;
    const int px  = (pid & 7) * 2;
    const int py  = (pid >> 3) * 2;

    float acc[5][2][2];
#pragma unroll
    for (int m = 0; m < 5; m++)
#pragma unroll
        for (int r = 0; r < 2; r++)
#pragma unroll
            for (int c = 0; c < 2; c++) acc[m][r][c] = 0.f;

    for (int ch9 = 0; ch9 < 9; ++ch9) {
        const float* in = &sIn[ch9 * 420];
#pragma unroll
        for (int dy = 0; dy < 5; ++dy) {
            float ra[6], rb[6];
#pragma unroll
            for (int k = 0; k < 6; k++) {
                ra[k] = in[(py + dy) * 21 + px + k];
                rb[k] = in[(py + 1 + dy) * 21 + px + k];
            }
#pragma unroll
            for (int dx = 0; dx < 5; ++dx) {
#pragma unroll
                for (int m = 0; m < 5; m++) {
                    float wv = sW[(mcg * 5 + m) * 225 + ch9 * 25 + dy * 5 + dx];
                    acc[m][0][0] += ra[dx] * wv;
                    acc[m][0][1] += ra[dx + 1] * wv;
                    acc[m][1][0] += rb[dx] * wv;
                    acc[m][1][1] += rb[dx + 1] * wv;
                }
            }
        }
    }

#pragma unroll
    for (int m = 0; m < 5; m++) {
        int mc = mcg * 5 + m;
        float bias = b2a[mc];
        int gp = uv * 20 + mc;
#pragma unroll
        for (int r = 0; r < 2; r++) {
            int y = ty0 + py + r;
            if (y >= 100) continue;
#pragma unroll
            for (int c = 0; c < 2; c++) {
                int x = tx0 + px + c;
                if (x >= 100) continue;
                Bn[((b * 100 + y) * 100 + x) * 192 + gp] = f2bf(fmaxf(acc[m][r][c] + bias, 0.f));
                if (uv == 0 && mcg == 3) {
#pragma unroll
                    for (int z = 0; z < 12; ++z)
                        Bn[((b * 100 + y) * 100 + x) * 192 + 180 + z] = 0;
                }
            }
        }
    }
}

// ---------------- MFMA conv: LDS halo + register weight prefetch ----------------
#define MFMA16(A0, A1, A2, A3, B0, B1, B2, B3)                                          \
    {                                                                                   \
        __builtin_amdgcn_s_setprio(1);                                                  \
        acc[0][0] = __builtin_amdgcn_mfma_f32_16x16x32_bf16(A0, B0, acc[0][0], 0, 0, 0);\
        acc[0][1] = __builtin_amdgcn_mfma_f32_16x16x32_bf16(A0, B1, acc[0][1], 0, 0, 0);\
        acc[0][2] = __builtin_amdgcn_mfma_f32_16x16x32_bf16(A0, B2, acc[0][2], 0, 0, 0);\
        acc[0][3] = __builtin_amdgcn_mfma_f32_16x16x32_bf16(A0, B3, acc[0][3], 0, 0, 0);\
        acc[1][0] = __builtin_amdgcn_mfma_f32_16x16x32_bf16(A1, B0, acc[1][0], 0, 0, 0);\
        acc[1][1] = __builtin_amdgcn_mfma_f32_16x16x32_bf16(A1, B1, acc[1][1], 0, 0, 0);\
        acc[1][2] = __builtin_amdgcn_mfma_f32_16x16x32_bf16(A1, B2, acc[1][2], 0, 0, 0);\
        acc[1][3] = __builtin_amdgcn_mfma_f32_16x16x32_bf16(A1, B3, acc[1][3], 0, 0, 0);\
        acc[2][0] = __builtin_amdgcn_mfma_f32_16x16x32_bf16(A2, B0, acc[2][0], 0, 0, 0);\
        acc[2][1] = __builtin_amdgcn_mfma_f32_16x16x32_bf16(A2, B1, acc[2][1], 0, 0, 0);\
        acc[2][2] = __builtin_amdgcn_mfma_f32_16x16x32_bf16(A2, B2, acc[2][2], 0, 0, 0);\
        acc[2][3] = __builtin_amdgcn_mfma_f32_16x16x32_bf16(A2, B3, acc[2][3], 0, 0, 0);\
        acc[3][0] = __builtin_amdgcn_mfma_f32_16x16x32_bf16(A3, B0, acc[3][0], 0, 0, 0);\
        acc[3][1] = __builtin_amdgcn_mfma_f32_16x16x32_bf16(A3, B1, acc[3][1], 0, 0, 0);\
        acc[3][2] = __builtin_amdgcn_mfma_f32_16x16x32_bf16(A3, B2, acc[3][2], 0, 0, 0);\
        acc[3][3] = __builtin_amdgcn_mfma_f32_16x16x32_bf16(A3, B3, acc[3][3], 0, 0, 0);\
        __builtin_amdgcn_s_setprio(0);                                                  \
    }

__global__ __launch_bounds__(256, 2) void conv_mfma_kernel(
    const unsigned short* __restrict__ Pn, const unsigned short* __restrict__ Bn,
    const unsigned short* __restrict__ WpA, const unsigned short* __restrict__ WpB,
    const float* __restrict__ b1, const float* __restrict__ b2b,
    float* __restrict__ out) {
    __shared__ __align__(16) unsigned short sHalo[4 * HSLOT * 8];  // 36,864 B

    const int tid  = threadIdx.x;
    const int lane = tid & 63, w = tid >> 6;
    const int l15  = lane & 15, lhi = lane >> 4;
    const int ocB  = blockIdx.y;
    const int pb   = blockIdx.x;
    const int b    = pb / 36;
    const int t36  = pb % 36;
    const int ty0  = (t36 / 3) * 8;
    const int tx0  = (t36 % 3) * 32;

    // A-fragment base: slot lhi, wave rows 2w..2w+1, col l15
    const int vA = (lhi * HSLOT + w * 72 + l15) * 8;

    float bb2[4], bb1[4];
#pragma unroll
    for (int n = 0; n < 4; ++n) {
        int oc  = ocB * 64 + n * 16 + l15;
        int occ = oc < 400 ? oc : 399;
        bb2[n] = b2b[occ];
        bb1[n] = b1[occ];
    }

    f32x4 acc[4][4] = {};

    auto stage_halo = [&](int seg) {
        if (seg < 6) {  // phase A: Bn halo 12x36, wave w stages k-slot w
            for (int L2 = 0; L2 < 7; ++L2) {
                int p = L2 * 64 + lane;
                if (p >= 432) p = 0;
                int hy = (p * 58255) >> 21;  // p/36
                int hx = p - hy * 36;
                gload16(Bn + ((size_t)((b * 100 + ty0 + hy) * 100 + tx0 + hx)) * 192 +
                            seg * 32 + w * 8,
                        &sHalo[(w * HSLOT + L2 * 64) * 8]);
            }
        } else {        // phase B: Pn halo 16x36 (seg7 origin +5 cols)
            int cx = tx0 + (seg == 7 ? 5 : 0);
            for (int L2 = 0; L2 < 9; ++L2) {
                int p = L2 * 64 + lane;
                int hy = (p * 58255) >> 21;
                int hx = p - hy * 36;
                int gx = cx + hx;
                gx = gx > 103 ? 103 : gx;    // clamped col never read
                gload16(Pn + ((size_t)((b * 104 + ty0 + hy) * 104 + gx)) * 32 + w * 8,
                        &sHalo[(w * HSLOT + L2 * 64) * 8]);
            }
        }
    };

    auto computeA = [&](int cc) {
        const unsigned short* wp = WpA + ((size_t)(cc * 25 * 7 + ocB)) * 2048 + lane * 8;
        bf16x8 c0 = *(const bf16x8*)(wp);
        bf16x8 c1 = *(const bf16x8*)(wp + 512);
        bf16x8 c2 = *(const bf16x8*)(wp + 1024);
        bf16x8 c3 = *(const bf16x8*)(wp + 1536);
        for (int dy = 0; dy < 5; ++dy) {
            const unsigned short* ha = &sHalo[vA + dy * 288];
#pragma unroll
            for (int dx = 0; dx < 5; ++dx) {
                wp += WST;  // next tap (over-read after cc=5 tap24 lands in WpB: benign)
                bf16x8 n0 = *(const bf16x8*)(wp);
                bf16x8 n1 = *(const bf16x8*)(wp + 512);
                bf16x8 n2 = *(const bf16x8*)(wp + 1024);
                bf16x8 n3 = *(const bf16x8*)(wp + 1536);
                bf16x8 a0 = *(const bf16x8*)&ha[dx * 8];
                bf16x8 a1 = *(const bf16x8*)&ha[dx * 8 + 128];
                bf16x8 a2 = *(const bf16x8*)&ha[dx * 8 + 288];
                bf16x8 a3 = *(const bf16x8*)&ha[dx * 8 + 416];
                MFMA16(a0, a1, a2, a3, c0, c1, c2, c3);
                c0 = n0; c1 = n1; c2 = n2; c3 = n3;
            }
        }
    };

    auto computeB1 = [&]() {  // taps dy0..8 x dx0..4 (visit order 0..44)
        const unsigned short* wp = WpB + (size_t)ocB * 2048 + lane * 8;
        bf16x8 c0 = *(const bf16x8*)(wp);
        bf16x8 c1 = *(const bf16x8*)(wp + 512);
        bf16x8 c2 = *(const bf16x8*)(wp + 1024);
        bf16x8 c3 = *(const bf16x8*)(wp + 1536);
        for (int dy = 0; dy < 9; ++dy) {
            const unsigned short* ha = &sHalo[vA + dy * 288];
#pragma unroll
            for (int dx = 0; dx < 5; ++dx) {
                wp += WST;
                bf16x8 n0 = *(const bf16x8*)(wp);
                bf16x8 n1 = *(const bf16x8*)(wp + 512);
                bf16x8 n2 = *(const bf16x8*)(wp + 1024);
                bf16x8 n3 = *(const bf16x8*)(wp + 1536);
                bf16x8 a0 = *(const bf16x8*)&ha[dx * 8];
                bf16x8 a1 = *(const bf16x8*)&ha[dx * 8 + 128];
                bf16x8 a2 = *(const bf16x8*)&ha[dx * 8 + 288];
                bf16x8 a3 = *(const bf16x8*)&ha[dx * 8 + 416];
                MFMA16(a0, a1, a2, a3, c0, c1, c2, c3);
                c0 = n0; c1 = n1; c2 = n2; c3 = n3;
            }
        }
    };

    auto computeB2 = [&]() {  // taps dy0..8 x dx5..8 (visit order 45..80)
        const unsigned short* wp = WpB + (size_t)(45 * 7 + ocB) * 2048 + lane * 8;
        bf16x8 c0 = *(const bf16x8*)(wp);
        bf16x8 c1 = *(const bf16x8*)(wp + 512);
        bf16x8 c2 = *(const bf16x8*)(wp + 1024);
        bf16x8 c3 = *(const bf16x8*)(wp + 1536);
        for (int dy = 0; dy < 9; ++dy) {
            const unsigned short* ha = &sHalo[vA + dy * 288];
#pragma unroll
            for (int dxl = 0; dxl < 4; ++dxl) {
                wp += WST;
                bf16x8 n0 = c0, n1 = c1, n2 = c2, n3 = c3;
                if (dy < 8 || dxl < 3) {  // don't read past WpB end on last tap
                    n0 = *(const bf16x8*)(wp);
                    n1 = *(const bf16x8*)(wp + 512);
                    n2 = *(const bf16x8*)(wp + 1024);
                    n3 = *(const bf16x8*)(wp + 1536);
                }
                bf16x8 a0 = *(const bf16x8*)&ha[dxl * 8];
                bf16x8 a1 = *(const bf16x8*)&ha[dxl * 8 + 128];
                bf16x8 a2 = *(const bf16x8*)&ha[dxl * 8 + 288];
                bf16x8 a3 = *(const bf16x8*)&ha[dxl * 8 + 416];
                MFMA16(a0, a1, a2, a3, c0, c1, c2, c3);
                c0 = n0; c1 = n1; c2 = n2; c3 = n3;
            }
        }
    };

    // ---------------- main flow: 8 halo segments ----------------
    stage_halo(0);
    __syncthreads();
    computeA(0);
    for (int cc = 1; cc < 6; ++cc) {
        __syncthreads();        // all reads of old halo done
        stage_halo(cc);
        __syncthreads();        // implicit vmcnt(0): halo landed
        computeA(cc);
    }

    __syncthreads();
    stage_halo(6);
    // p2 = relu(p2 + b2b) while halo lands
#pragma unroll
    for (int m = 0; m < 4; ++m)
#pragma unroll
        for (int n = 0; n < 4; ++n)
#pragma unroll
            for (int i = 0; i < 4; ++i)
                acc[m][n][i] = fmaxf(acc[m][n][i] + bb2[n], 0.f);
    __syncthreads();
    computeB1();

    __syncthreads();
    stage_halo(7);
    __syncthreads();
    computeB2();

    // ---------------- epilogue: (p1+p2+b1)/2, pixel-shuffled ----------------
#pragma unroll
    for (int n = 0; n < 4; ++n) {
        int oc = ocB * 64 + n * 16 + l15;
        if (oc >= 400) continue;
        float bv = bb1[n];
        int c25 = oc >> 4, r1 = (oc >> 2) & 3, r2 = oc & 3;
#pragma unroll
        for (int m = 0; m < 4; ++m) {
            int y  = ty0 + w * 2 + (m >> 1);
            int x0 = tx0 + (m & 1) * 16 + lhi * 4;
#pragma unroll
            for (int i = 0; i < 4; ++i) {
                out[((size_t)(b * 25 + c25) * 384 + y * 4 + r1) * 384 + (x0 + i) * 4 + r2] =
                    (acc[m][n][i] + bv) * 0.5f;
            }
        }
    }
}

extern "C" void kernel_launch(void* const* d_in, const int* in_sizes, int n_in,
                              void* d_out, int out_size, void* d_ws, size_t ws_size,
                              hipStream_t stream) {
    const float* pic = (const float*)d_in[0];
    const float* w1  = (const float*)d_in[1];
    const float* b1  = (const float*)d_in[2];
    const float* w2a = (const float*)d_in[3];
    const float* b2a = (const float*)d_in[4];
    const float* w2b = (const float*)d_in[5];
    const float* b2b = (const float*)d_in[6];
    float* out = (float*)d_out;

    char* ws = (char*)d_ws;
    unsigned short* Pn  = (unsigned short*)(ws);             // 1,384,448 B
    unsigned short* Bn  = (unsigned short*)(ws + 1384448);   // 7,680,000 B
    unsigned short* WpA = (unsigned short*)(ws + 9064448);   // 4,300,800 B
    unsigned short* WpB = (unsigned short*)(ws + 13365248);  // 2,322,432 B
    unsigned short* Pp  = WpA;  // planar bf16 P aliases WpA (dead before prep_w)

    pad_kernel<<<(NB * 104 * 104 + 255) / 256, 256, 0, stream>>>(pic, Pn, Pp);
    conv2a_kernel<<<dim3(49, 9, NB), 256, 0, stream>>>(Pp, w2a, b2a, Bn);
    prep_w_kernel<<<(NWA + NWB + 255) / 256, 256, 0, stream>>>(w2b, w1, WpA, WpB);
    conv_mfma_kernel<<<dim3(72, 7), 256, 0, stream>>>(Pn, Bn, WpA, WpB, b1, b2b, out);
}

// Round 6
// 159.928 us; speedup vs baseline: 1.7541x; 1.0734x over previous
//
#include <hip/hip_runtime.h>
#include <hip/hip_bf16.h>

// ---------------------------------------------------------------------------
// DimNet via bf16 MFMA implicit GEMM, fully software-pipelined.
//   Pn  = padded input  NHWC bf16 [2][104][104][32]
//   Bn  = relu(conv2a)  NHWC bf16 [2][100][100][192] (g' = uv*20+mc, MFMA-made)
//   Wp  = packed weights, ONE linear array of 231 taps x WST:
//         [cc6][tap25][ocb7][frag4][lane64][8]  (w2b)  followed by
//         [tap81 visit-order][ocb7][frag4][lane64][8]  (w1)
// conv_mfma: 256 thr / 4 waves, 256px x 64oc, halo double-buffered in LDS,
//   A-frags + W-frags register double-buffered across taps, vmcnt(4) barriers.
// conv2a_mfma: same structure, K=32, weight frags built in LDS from w2a.
// ---------------------------------------------------------------------------

typedef __attribute__((ext_vector_type(8))) unsigned short ushort8;
typedef __attribute__((ext_vector_type(8))) __bf16 bf16x8;
typedef __attribute__((ext_vector_type(4))) float f32x4;

#define NB 2
#define HSLOT 576          // cells per k-slot (16 rows x 36 cols), main kernel
#define HBUF (4 * HSLOT * 8)  // ushorts per halo buffer = 18432
#define WST 14336          // ushorts per tap in packed weights (7*4*64*8)
#define NWA (6 * 25 * 7 * 4 * 64 * 8)   // 2,150,400
#define NWB (81 * 7 * 4 * 64 * 8)       // 1,161,216

static __device__ __forceinline__ unsigned short f2bf(float f) {
    __hip_bfloat16 h = __float2bfloat16(f);
    return *reinterpret_cast<unsigned short*>(&h);
}
static __device__ __forceinline__ void gload16(const unsigned short* g, unsigned short* l) {
    __builtin_amdgcn_global_load_lds(
        (const __attribute__((address_space(1))) unsigned int*)(const void*)g,
        (__attribute__((address_space(3))) unsigned int*)(void*)l, 16, 0, 0);
}

#define MFMA16(A0, A1, A2, A3, B0, B1, B2, B3)                                          \
    {                                                                                   \
        __builtin_amdgcn_s_setprio(1);                                                  \
        acc[0][0] = __builtin_amdgcn_mfma_f32_16x16x32_bf16(A0, B0, acc[0][0], 0, 0, 0);\
        acc[0][1] = __builtin_amdgcn_mfma_f32_16x16x32_bf16(A0, B1, acc[0][1], 0, 0, 0);\
        acc[0][2] = __builtin_amdgcn_mfma_f32_16x16x32_bf16(A0, B2, acc[0][2], 0, 0, 0);\
        acc[0][3] = __builtin_amdgcn_mfma_f32_16x16x32_bf16(A0, B3, acc[0][3], 0, 0, 0);\
        acc[1][0] = __builtin_amdgcn_mfma_f32_16x16x32_bf16(A1, B0, acc[1][0], 0, 0, 0);\
        acc[1][1] = __builtin_amdgcn_mfma_f32_16x16x32_bf16(A1, B1, acc[1][1], 0, 0, 0);\
        acc[1][2] = __builtin_amdgcn_mfma_f32_16x16x32_bf16(A1, B2, acc[1][2], 0, 0, 0);\
        acc[1][3] = __builtin_amdgcn_mfma_f32_16x16x32_bf16(A1, B3, acc[1][3], 0, 0, 0);\
        acc[2][0] = __builtin_amdgcn_mfma_f32_16x16x32_bf16(A2, B0, acc[2][0], 0, 0, 0);\
        acc[2][1] = __builtin_amdgcn_mfma_f32_16x16x32_bf16(A2, B1, acc[2][1], 0, 0, 0);\
        acc[2][2] = __builtin_amdgcn_mfma_f32_16x16x32_bf16(A2, B2, acc[2][2], 0, 0, 0);\
        acc[2][3] = __builtin_amdgcn_mfma_f32_16x16x32_bf16(A2, B3, acc[2][3], 0, 0, 0);\
        acc[3][0] = __builtin_amdgcn_mfma_f32_16x16x32_bf16(A3, B0, acc[3][0], 0, 0, 0);\
        acc[3][1] = __builtin_amdgcn_mfma_f32_16x16x32_bf16(A3, B1, acc[3][1], 0, 0, 0);\
        acc[3][2] = __builtin_amdgcn_mfma_f32_16x16x32_bf16(A3, B2, acc[3][2], 0, 0, 0);\
        acc[3][3] = __builtin_amdgcn_mfma_f32_16x16x32_bf16(A3, B3, acc[3][3], 0, 0, 0);\
        __builtin_amdgcn_s_setprio(0);                                                  \
    }

// ---------------- pad: NHWC bf16 ----------------
__global__ __launch_bounds__(256) void pad_kernel(const float* __restrict__ pic,
                                                  unsigned short* __restrict__ Pn) {
    int idx = blockIdx.x * 256 + threadIdx.x;
    if (idx >= NB * 104 * 104) return;
    int x = idx % 104;
    int y = (idx / 104) % 104;
    int b = idx / (104 * 104);
    unsigned short vals[32];
    bool inter = (y >= 4 && y < 100 && x >= 4 && x < 100);
#pragma unroll
    for (int c = 0; c < 25; ++c) {
        float v = inter ? pic[((b * 25 + c) * 96 + (y - 4)) * 96 + (x - 4)] : 0.5f;
        vals[c] = f2bf(v);
    }
#pragma unroll
    for (int c = 25; c < 32; ++c) vals[c] = 0;
    ushort8* dst = (ushort8*)(Pn + idx * 32);
#pragma unroll
    for (int j = 0; j < 4; ++j) dst[j] = *(ushort8*)&vals[j * 8];
}

// ---------------- weight prep: pack w2b + w1 in fragment order ----------------
__global__ __launch_bounds__(256) void prep_w_kernel(const float* __restrict__ w2b,
                                                     const float* __restrict__ w1,
                                                     unsigned short* __restrict__ Wp) {
    int idx = blockIdx.x * 256 + threadIdx.x;
    if (idx < NWA) {
        int e = idx & 7, lane = (idx >> 3) & 63, n = (idx >> 9) & 3;
        int r = idx >> 11;
        int ocb = r % 7; r /= 7;
        int tap = r % 25; int cc = r / 25;
        int oc = ocb * 64 + n * 16 + (lane & 15);
        int k  = cc * 32 + (lane >> 4) * 8 + e;      // g' channel
        float v = 0.f;
        if (oc < 400 && k < 180) {
            int mc = k % 20, uv = k / 20;            // g' = uv*20 + mc
            v = w2b[oc * 4500 + (mc * 9 + uv) * 25 + tap];
        }
        Wp[idx] = f2bf(v);
    } else {
        int kx = idx - NWA;
        if (kx >= NWB) return;
        int e = kx & 7, lane = (kx >> 3) & 63, n = (kx >> 9) & 3;
        int r = kx >> 11;
        int ocb = r % 7; int tp = r / 7;             // visit order 0..80
        int dy, dx;
        if (tp < 45) { dy = tp / 5; dx = tp % 5; }
        else { int u = tp - 45; dy = u >> 2; dx = 5 + (u & 3); }
        int oc = ocb * 64 + n * 16 + (lane & 15);
        int c  = (lane >> 4) * 8 + e;
        float v = (oc < 400 && c < 25) ? w1[oc * 2025 + c * 81 + (dy * 9 + dx)] : 0.f;
        Wp[NWA + kx] = f2bf(v);
    }
}

// ---------------- conv2a via MFMA (K=32, weight frags built in LDS) ----------------
__global__ __launch_bounds__(256) void conv2a_mfma_kernel(
    const unsigned short* __restrict__ Pn, const float* __restrict__ w2a,
    const float* __restrict__ b2a, unsigned short* __restrict__ Bn) {
    __shared__ __align__(16) unsigned short sWc[25 * 2048];     // 102,400 B
    __shared__ __align__(16) unsigned short sHalo[4 * 448 * 8]; //  28,672 B

    const int tid  = threadIdx.x;
    const int lane = tid & 63, w = tid >> 6;
    const int l15  = lane & 15, lhi = lane >> 4;
    const int gx0  = blockIdx.x;          // 0..103
    const int b    = gx0 / 52, t52 = gx0 % 52;
    const int ty0  = (t52 >> 2) * 8;      // 0..96
    const int tx0  = (t52 & 3) * 32;      // 0,32,64,96
    const int ocB  = blockIdx.y;          // 0..2

    // ---- build weight fragments: thread (n=w, lane) owns 8 e-slots ----
    {
        int oc = ocB * 64 + w * 16 + (lane & 15);
        int kb = (lane >> 4) * 8;
        int uv = oc / 20;
        int mc = oc - uv * 20;
        int u = uv / 3, v = uv - (uv / 3) * 3;
        const float* wb[8];
#pragma unroll
        for (int e = 0; e < 8; ++e) {
            int k  = kb + e;
            int c1 = k / 5, c2 = k - (k / 5) * 5;
            int da1 = c1 - u, da2 = c2 - v;
            bool valid = (oc < 180) && ((unsigned)da1 < 3u) && ((unsigned)da2 < 3u);
            wb[e] = valid ? (w2a + mc * 225 + (da1 * 3 + da2) * 25) : (const float*)0;
        }
#pragma unroll
        for (int tap = 0; tap < 25; ++tap) {
            unsigned short fr[8];
#pragma unroll
            for (int e = 0; e < 8; ++e) fr[e] = wb[e] ? f2bf(wb[e][tap]) : (unsigned short)0;
            *(ushort8*)&sWc[tap * 2048 + tid * 8] = *(ushort8*)fr;
        }
    }

    // ---- halo stage: wave w -> k-slot w, 12x36, edge-clamped ----
    for (int L2 = 0; L2 < 7; ++L2) {
        int p = L2 * 64 + lane;
        if (p >= 432) p = 0;
        int hy = (p * 58255) >> 21, hx = p - hy * 36;
        int gy = ty0 + hy; gy = gy > 103 ? 103 : gy;
        int gx = tx0 + hx; gx = gx > 103 ? 103 : gx;
        gload16(Pn + ((size_t)((b * 104 + gy) * 104 + gx)) * 32 + w * 8,
                &sHalo[(w * 448 + L2 * 64) * 8]);
    }
    float bs[4];
#pragma unroll
    for (int n = 0; n < 4; ++n) {
        int oc = ocB * 64 + n * 16 + l15;
        bs[n] = (oc < 180) ? b2a[oc % 20] : 0.f;
    }
    __syncthreads();

    const unsigned short* hb = &sHalo[(lhi * 448 + w * 72 + l15) * 8];
    const unsigned short* wc = &sWc[lane * 8];

    f32x4 acc[4][4] = {};
    bf16x8 a0 = *(const bf16x8*)(hb), a1 = *(const bf16x8*)(hb + 128);
    bf16x8 a2 = *(const bf16x8*)(hb + 288), a3 = *(const bf16x8*)(hb + 416);
    bf16x8 c0 = *(const bf16x8*)(wc), c1 = *(const bf16x8*)(wc + 512);
    bf16x8 c2 = *(const bf16x8*)(wc + 1024), c3 = *(const bf16x8*)(wc + 1536);
    bf16x8 q0, q1, q2, q3, n0, n1, n2, n3;
#pragma unroll
    for (int t = 0; t < 25; ++t) {
        if (t < 24) {
            const int u = (((t + 1) / 5) * 36 + ((t + 1) % 5)) * 8;
            q0 = *(const bf16x8*)(hb + u);
            q1 = *(const bf16x8*)(hb + u + 128);
            q2 = *(const bf16x8*)(hb + u + 288);
            q3 = *(const bf16x8*)(hb + u + 416);
            const unsigned short* wn = wc + (t + 1) * 2048;
            n0 = *(const bf16x8*)(wn);
            n1 = *(const bf16x8*)(wn + 512);
            n2 = *(const bf16x8*)(wn + 1024);
            n3 = *(const bf16x8*)(wn + 1536);
        }
        MFMA16(a0, a1, a2, a3, c0, c1, c2, c3);
        if (t < 24) { a0 = q0; a1 = q1; a2 = q2; a3 = q3;
                      c0 = n0; c1 = n1; c2 = n2; c3 = n3; }
    }

    // epilogue: relu(acc + bias) -> Bn, masked to 100x100
#pragma unroll
    for (int n = 0; n < 4; ++n) {
        int oc = ocB * 64 + n * 16 + l15;
#pragma unroll
        for (int m = 0; m < 4; ++m) {
            int y = ty0 + w * 2 + (m >> 1);
            if (y >= 100) continue;
            int x0 = tx0 + (m & 1) * 16 + lhi * 4;
#pragma unroll
            for (int i = 0; i < 4; ++i) {
                int x = x0 + i;
                if (x >= 100) continue;
                Bn[((size_t)((b * 100 + y) * 100 + x)) * 192 + oc] =
                    f2bf(fmaxf(acc[m][n][i] + bs[n], 0.f));
            }
        }
    }
}

// ---------------- main MFMA conv: dbuf halo + full register pipeline ----------------
__global__ __launch_bounds__(256, 2) void conv_mfma_kernel(
    const unsigned short* __restrict__ Pn, const unsigned short* __restrict__ Bn,
    const unsigned short* __restrict__ Wp, const float* __restrict__ b1,
    const float* __restrict__ b2b, float* __restrict__ out) {
    __shared__ __align__(16) unsigned short sHalo[2 * HBUF];  // 73,728 B

    const int tid  = threadIdx.x;
    const int lane = tid & 63, w = tid >> 6;
    const int l15  = lane & 15, lhi = lane >> 4;
    const int ocB  = blockIdx.y;
    const int pb   = blockIdx.x;
    const int b    = pb / 36;
    const int t36  = pb % 36;
    const int ty0  = (t36 / 3) * 8;
    const int tx0  = (t36 % 3) * 32;

    const int vA = (lhi * HSLOT + w * 72 + l15) * 8;

    auto stageA = [&](int cc, int par) {  // Bn halo 12x36, chunk cc
        unsigned short* dst0 = &sHalo[par * HBUF + w * HSLOT * 8];
        for (int L2 = 0; L2 < 7; ++L2) {
            int p = L2 * 64 + lane;
            if (p >= 432) p = 0;
            int hy = (p * 58255) >> 21, hx = p - hy * 36;
            gload16(Bn + ((size_t)((b * 100 + ty0 + hy) * 100 + tx0 + hx)) * 192 +
                        cc * 32 + w * 8,
                    dst0 + L2 * 512);
        }
    };
    auto stageB = [&](int seg, int par) {  // Pn halo 16x36
        int cx = tx0 + (seg == 7 ? 5 : 0);
        unsigned short* dst0 = &sHalo[par * HBUF + w * HSLOT * 8];
        for (int L2 = 0; L2 < 9; ++L2) {
            int p = L2 * 64 + lane;
            int hy = (p * 58255) >> 21, hx = p - hy * 36;
            int gx = cx + hx;
            gx = gx > 103 ? 103 : gx;     // clamped col never feeds valid output
            gload16(Pn + ((size_t)((b * 104 + ty0 + hy) * 104 + gx)) * 32 + w * 8,
                    dst0 + L2 * 512);
        }
    };

    float bb2[4], bb1[4];
#pragma unroll
    for (int n = 0; n < 4; ++n) {
        int oc  = ocB * 64 + n * 16 + l15;
        int occ = oc < 400 ? oc : 399;
        bb2[n] = b2b[occ];
        bb1[n] = b1[occ];
    }

    const unsigned short* wq = Wp + ocB * 2048 + lane * 8;   // tap g=0
    bf16x8 c0 = *(const bf16x8*)(wq);
    bf16x8 c1 = *(const bf16x8*)(wq + 512);
    bf16x8 c2 = *(const bf16x8*)(wq + 1024);
    bf16x8 c3 = *(const bf16x8*)(wq + 1536);
    stageA(0, 0);
    __syncthreads();   // drains vmcnt(0): halo0 + c-frags landed

    f32x4 acc[4][4] = {};
    bf16x8 a0, a1, a2, a3, q0, q1, q2, q3, n0, n1, n2, n3;

    // -------- phase A: 6 segments x 25 taps --------
    for (int cc = 0; cc < 6; ++cc) {
        const unsigned short* hb = &sHalo[(cc & 1) * HBUF + vA];
        a0 = *(const bf16x8*)(hb);
        a1 = *(const bf16x8*)(hb + 128);
        a2 = *(const bf16x8*)(hb + 288);
        a3 = *(const bf16x8*)(hb + 416);
        if (cc < 5) stageA(cc + 1, (cc + 1) & 1);
        else        stageB(6, 0);
#pragma unroll
        for (int t = 0; t < 25; ++t) {
            wq += WST;
            n0 = *(const bf16x8*)(wq);
            n1 = *(const bf16x8*)(wq + 512);
            n2 = *(const bf16x8*)(wq + 1024);
            n3 = *(const bf16x8*)(wq + 1536);
            if (t < 24) {
                const int u = (((t + 1) / 5) * 36 + ((t + 1) % 5)) * 8;
                q0 = *(const bf16x8*)(hb + u);
                q1 = *(const bf16x8*)(hb + u + 128);
                q2 = *(const bf16x8*)(hb + u + 288);
                q3 = *(const bf16x8*)(hb + u + 416);
            }
            MFMA16(a0, a1, a2, a3, c0, c1, c2, c3);
            c0 = n0; c1 = n1; c2 = n2; c3 = n3;
            if (t < 24) { a0 = q0; a1 = q1; a2 = q2; a3 = q3; }
        }
        if (cc == 5) {  // p2 = relu(p2 + b2b)
#pragma unroll
            for (int m = 0; m < 4; ++m)
#pragma unroll
                for (int n = 0; n < 4; ++n)
#pragma unroll
                    for (int i = 0; i < 4; ++i)
                        acc[m][n][i] = fmaxf(acc[m][n][i] + bb2[n], 0.f);
        }
        asm volatile("s_waitcnt vmcnt(4)" ::: "memory");
        asm volatile("s_barrier" ::: "memory");
    }

    // -------- phase B1: 45 taps (dy 0..8, dx 0..4), halo parity 0 --------
    {
        const unsigned short* hb = &sHalo[vA];
        a0 = *(const bf16x8*)(hb);
        a1 = *(const bf16x8*)(hb + 128);
        a2 = *(const bf16x8*)(hb + 288);
        a3 = *(const bf16x8*)(hb + 416);
        stageB(7, 1);
#pragma unroll
        for (int t = 0; t < 45; ++t) {
            wq += WST;
            n0 = *(const bf16x8*)(wq);
            n1 = *(const bf16x8*)(wq + 512);
            n2 = *(const bf16x8*)(wq + 1024);
            n3 = *(const bf16x8*)(wq + 1536);
            if (t < 44) {
                const int u = (((t + 1) / 5) * 36 + ((t + 1) % 5)) * 8;
                q0 = *(const bf16x8*)(hb + u);
                q1 = *(const bf16x8*)(hb + u + 128);
                q2 = *(const bf16x8*)(hb + u + 288);
                q3 = *(const bf16x8*)(hb + u + 416);
            }
            MFMA16(a0, a1, a2, a3, c0, c1, c2, c3);
            c0 = n0; c1 = n1; c2 = n2; c3 = n3;
            if (t < 44) { a0 = q0; a1 = q1; a2 = q2; a3 = q3; }
        }
        asm volatile("s_waitcnt vmcnt(4)" ::: "memory");
        asm volatile("s_barrier" ::: "memory");
    }

    // -------- phase B2: 36 taps (dy 0..8, dx 5..8), halo parity 1 --------
    {
        const unsigned short* hb = &sHalo[HBUF + vA];
        a0 = *(const bf16x8*)(hb);
        a1 = *(const bf16x8*)(hb + 128);
        a2 = *(const bf16x8*)(hb + 288);
        a3 = *(const bf16x8*)(hb + 416);
#pragma unroll
        for (int t = 0; t < 36; ++t) {
            if (t < 35) {
                wq += WST;
                n0 = *(const bf16x8*)(wq);
                n1 = *(const bf16x8*)(wq + 512);
                n2 = *(const bf16x8*)(wq + 1024);
                n3 = *(const bf16x8*)(wq + 1536);
                const int u = (((t + 1) / 4) * 36 + ((t + 1) % 4)) * 8;
                q0 = *(const bf16x8*)(hb + u);
                q1 = *(const bf16x8*)(hb + u + 128);
                q2 = *(const bf16x8*)(hb + u + 288);
                q3 = *(const bf16x8*)(hb + u + 416);
            }
            MFMA16(a0, a1, a2, a3, c0, c1, c2, c3);
            if (t < 35) { a0 = q0; a1 = q1; a2 = q2; a3 = q3;
                          c0 = n0; c1 = n1; c2 = n2; c3 = n3; }
        }
    }

    // -------- epilogue: (p1+p2+b1)/2, pixel-shuffled --------
#pragma unroll
    for (int n = 0; n < 4; ++n) {
        int oc = ocB * 64 + n * 16 + l15;
        if (oc >= 400) continue;
        float bv = bb1[n];
        int c25 = oc >> 4, r1 = (oc >> 2) & 3, r2 = oc & 3;
#pragma unroll
        for (int m = 0; m < 4; ++m) {
            int y  = ty0 + w * 2 + (m >> 1);
            int x0 = tx0 + (m & 1) * 16 + lhi * 4;
#pragma unroll
            for (int i = 0; i < 4; ++i) {
                out[((size_t)(b * 25 + c25) * 384 + y * 4 + r1) * 384 + (x0 + i) * 4 + r2] =
                    (acc[m][n][i] + bv) * 0.5f;
            }
        }
    }
}

extern "C" void kernel_launch(void* const* d_in, const int* in_sizes, int n_in,
                              void* d_out, int out_size, void* d_ws, size_t ws_size,
                              hipStream_t stream) {
    const float* pic = (const float*)d_in[0];
    const float* w1  = (const float*)d_in[1];
    const float* b1  = (const float*)d_in[2];
    const float* w2a = (const float*)d_in[3];
    const float* b2a = (const float*)d_in[4];
    const float* w2b = (const float*)d_in[5];
    const float* b2b = (const float*)d_in[6];
    float* out = (float*)d_out;

    char* ws = (char*)d_ws;
    unsigned short* Pn = (unsigned short*)(ws);             // 1,384,448 B
    unsigned short* Bn = (unsigned short*)(ws + 1384448);   // 7,680,000 B
    unsigned short* Wp = (unsigned short*)(ws + 9064448);   // WpA(4,300,800)+WpB(2,322,432), contiguous

    pad_kernel<<<(NB * 104 * 104 + 255) / 256, 256, 0, stream>>>(pic, Pn);
    prep_w_kernel<<<(NWA + NWB + 255) / 256, 256, 0, stream>>>(w2b, w1, Wp);
    conv2a_mfma_kernel<<<dim3(104, 3), 256, 0, stream>>>(Pn, w2a, b2a, Bn);
    conv_mfma_kernel<<<dim3(72, 7), 256, 0, stream>>>(Pn, Bn, Wp, b1, b2b, out);
}